// Round 14
// baseline (38.558 us; speedup 1.0000x reference)
//
#include <hip/hip_runtime.h>

#define NN 128     // modes
#define CHUNK 32   // layers staged per LDS buffer
#define NCH 8      // 8 chunks x 32 = 256 staged rows (row 255 clamped to 254)

typedef const __attribute__((address_space(1))) void* gptr_t;
typedef __attribute__((address_space(3))) void* lptr_t;

// ---- whole-wave lane shifts via DPP (wave_shl:1 / wave_shr:1), proven R9/R11 ----
__device__ __forceinline__ float wshl1(float x) {   // lane i <- lane i+1
    return __int_as_float(__builtin_amdgcn_update_dpp(
        __float_as_int(x), __float_as_int(x), 0x130, 0xf, 0xf, false));
}
__device__ __forceinline__ float wshr1(float x) {   // lane i <- lane i-1
    return __int_as_float(__builtin_amdgcn_update_dpp(
        __float_as_int(x), __float_as_int(x), 0x138, 0xf, 0xf, false));
}

// ---------------- kernel 1: (cos,sin) table ----------------
// tab[j*128+m] = (cos th, sin th), th = theta_even[j,m]  (261 KB in d_ws)
__global__ __launch_bounds__(256) void coef_kernel(
    const float* __restrict__ th_ev, float2* __restrict__ tab)
{
    int i = blockIdx.x * 256 + threadIdx.x;
    if (i < 255 * 128) {
        float s, c;
        __sincosf(th_ev[i], &s, &c);
        tab[i] = make_float2(c, s);
    }
}

// ---------------- kernel 2: mesh evolution, LDS-staged, 8-layer DS batches ----------------
// One wave per column c (128 blocks). Lane l holds rows 4l..4l+3 (4 complex).
// Table staged global->LDS in 32-layer chunks (global_load_lds 16B/lane,
// double-buffered, counted vmcnt). Chunk consumed in batches of 8:
// 8 ds_read_b128 issued together -> compiler's counted lgkmcnt hides 7/8
// of the DS latency that R13 exposed per-layer.
__global__ __launch_bounds__(64) void mesh_lds_kernel(
    const float4* __restrict__ tab,        // (255*64) float4 rows: (c0,s0,c1,s1)
    const float* __restrict__ theta_in,    // (128,)
    const float* __restrict__ theta_out,   // (128,)
    float* __restrict__ out)               // (128,128) f32 = Re(arch)
{
    __shared__ float4 lbuf[2][CHUNK][64];  // 64 KB

    const int c = blockIdx.x;
    const int l = threadIdx.x;

    const float A  = sqrtf(0.95f * 0.505f);
    const float B  = sqrtf(0.95f * 0.495f);
    const float C2 = sqrtf(0.98f * 0.01f);
    const float S2 = sqrtf(0.98f * 0.99f);

    // branchless corner coeffs: row 0 (l==0, slot v0), row 255 (l==63, slot v3)
    const float ec0 = (l == 0)  ? S2 : C2, es0 = (l == 0)  ? 0.f : S2;
    const float ec3 = (l == 63) ? S2 : C2, es3 = (l == 63) ? 0.f : S2;

    // stage chunk ch into buffer nb: rows ch*32..ch*32+31 (clamped at 254)
    auto stage = [&](int ch, int nb) {
        #pragma unroll
        for (int s = 0; s < CHUNK; ++s) {
            int j = ch * CHUNK + s;
            if (j > 254) j = 254;
            __builtin_amdgcn_global_load_lds(
                (gptr_t)(tab + j * 64 + l),          // per-lane global src (16B)
                (lptr_t)(&lbuf[nb][s][0]),           // wave-uniform LDS base
                16, 0, 0);                           // lane l lands at base+l*16
        }
    };

    stage(0, 0);   // chunk 0 in flight while we init state below

    // init: column c after MMI_IN -> rows 2c: A e^{i th}, 2c+1: iB e^{i th}
    float2 v0 = make_float2(0.f, 0.f), v1 = v0, v2 = v0, v3 = v0;
    {
        float s, co;
        __sincosf(theta_in[c], &s, &co);
        float2 e0 = make_float2(A * co, A * s);
        float2 e1 = make_float2(-B * s, B * co);
        if (l == (c >> 1)) {
            if (c & 1) { v2 = e0; v3 = e1; }
            else       { v0 = e0; v1 = e1; }
        }
    }

    // rotate-then-mix layer (proven R11 math)
    auto layer = [&](float4 t) {
        float rx = t.x * v0.x - t.y * v0.y;     // e^{i th} * v0
        float ry = t.x * v0.y + t.y * v0.x;
        float qx = t.z * v2.x - t.w * v2.y;     // e^{i th'} * v2
        float qy = t.z * v2.y + t.w * v2.x;
        float2 n0, n1, n2, n3;
        n0.x = A * rx   - B * v1.y;  n0.y = A * ry   + B * v1.x;
        n1.x = A * v1.x - B * ry;    n1.y = A * v1.y + B * rx;
        n2.x = A * qx   - B * v3.y;  n2.y = A * qy   + B * v3.x;
        n3.x = A * v3.x - B * qy;    n3.y = A * v3.y + B * qx;
        v0 = n0; v1 = n1; v2 = n2; v3 = n3;
    };
    auto crossl = [&]() {
        float nx = wshl1(v0.x), ny = wshl1(v0.y);   // lane l+1's v0
        float px = wshr1(v3.x), py = wshr1(v3.y);   // lane l-1's v3
        float2 m0, m1, m2, m3;
        m0.x = ec0 * v0.x - es0 * py;  m0.y = ec0 * v0.y + es0 * px;
        m3.x = ec3 * v3.x - es3 * ny;  m3.y = ec3 * v3.y + es3 * nx;
        m1.x = C2 * v1.x - S2 * v2.y;  m1.y = C2 * v1.y + S2 * v2.x;
        m2.x = C2 * v2.x - S2 * v1.y;  m2.y = C2 * v2.y + S2 * v1.x;
        v0 = m0; v1 = m1; v2 = m2; v3 = m3;
    };

    // 8 layers per DS batch: 8 ds_read_b128 issued together, then 8 layers.
    // LB = &lbuf[buf][s0][l]; LB[s*64] = lbuf[buf][s0+s][l] (const ds offsets).
    auto batch8 = [&](const float4* LB) {
        float4 t0 = LB[0],   t1 = LB[64],  t2 = LB[128], t3 = LB[192],
               t4 = LB[256], t5 = LB[320], t6 = LB[384], t7 = LB[448];
        layer(t0); crossl(); layer(t1);
        layer(t2); crossl(); layer(t3);
        layer(t4); crossl(); layer(t5);
        layer(t6); crossl(); layer(t7);
    };

    float2 o0, o1;
    for (int ch = 0; ch < NCH; ++ch) {
        const int buf = ch & 1;
        if (ch + 1 < NCH) {
            stage(ch + 1, buf ^ 1);                            // prefetch next chunk
            asm volatile("s_waitcnt vmcnt(32)" ::: "memory");  // this chunk done
        } else {
            asm volatile("s_waitcnt vmcnt(0)" ::: "memory");
        }
        __builtin_amdgcn_sched_barrier(0);

        if (ch + 1 < NCH) {
            // 32 full layers; global j = ch*32+s, parity(j)=parity(s)
            batch8(&lbuf[buf][0][l]);
            batch8(&lbuf[buf][8][l]);
            batch8(&lbuf[buf][16][l]);
            batch8(&lbuf[buf][24][l]);
        } else {
            // last chunk: layers 224..253 (slots 0..29), slot 30 = theta[254] fold
            batch8(&lbuf[buf][0][l]);
            batch8(&lbuf[buf][8][l]);
            batch8(&lbuf[buf][16][l]);
            {   // slots 24..29 (layers 248..253) + fold coef (slot 30)
                const float4* LB = &lbuf[buf][24][l];
                float4 t0 = LB[0],   t1 = LB[64],  t2 = LB[128],
                       t3 = LB[192], t4 = LB[256], t5 = LB[320], t6 = LB[384];
                layer(t0); crossl(); layer(t1);
                layer(t2); crossl(); layer(t3);
                layer(t4); crossl(); layer(t5);
                // fold: diag(theta[254]) + MMI_OUT -> rows 2l, 2l+1
                float rx = t6.x * v0.x - t6.y * v0.y;
                float ry = t6.x * v0.y + t6.y * v0.x;
                float qx = t6.z * v2.x - t6.w * v2.y;
                float qy = t6.z * v2.y + t6.w * v2.x;
                o0.x = A * rx - B * v1.y;  o0.y = A * ry + B * v1.x;
                o1.x = A * qx - B * v3.y;  o1.y = A * qy + B * v3.x;
            }
        }
    }

    // diag(d_out) rotation, keep real part
    float2 tho = ((const float2*)theta_out)[l];
    float s0, c0, s1, c1;
    __sincosf(tho.x, &s0, &c0);
    __sincosf(tho.y, &s1, &c1);
    out[(2 * l)     * NN + c] = c0 * o0.x - s0 * o0.y;
    out[(2 * l + 1) * NN + c] = c1 * o1.x - s1 * o1.y;
}

// ---------------- fallback (proven R6-style): ws too small ----------------
struct CoefF { float2 a0, b0, a1, b1; };
__device__ __forceinline__ CoefF make_coef_f(float2 th) {
    const float A = sqrtf(0.95f * 0.505f);
    const float B = sqrtf(0.95f * 0.495f);
    float s0, c0, s1, c1;
    __sincosf(th.x, &s0, &c0);
    __sincosf(th.y, &s1, &c1);
    CoefF cf;
    cf.a0 = make_float2(A * c0, A * s0); cf.b0 = make_float2(-B * s0, B * c0);
    cf.a1 = make_float2(A * c1, A * s1); cf.b1 = make_float2(-B * s1, B * c1);
    return cf;
}
__global__ __launch_bounds__(64) void mesh_fallback(
    const float* __restrict__ theta_in, const float* __restrict__ theta_even,
    const float* __restrict__ theta_out, float* __restrict__ out)
{
    const int c = blockIdx.x, l = threadIdx.x;
    const float A  = sqrtf(0.95f * 0.505f);
    const float B  = sqrtf(0.95f * 0.495f);
    const float C2 = sqrtf(0.98f * 0.01f);
    const float S2 = sqrtf(0.98f * 0.99f);
    const float ec0 = (l == 0)  ? S2 : C2, es0 = (l == 0)  ? 0.f : S2;
    const float ec3 = (l == 63) ? S2 : C2, es3 = (l == 63) ? 0.f : S2;
    float2 v0 = make_float2(0.f, 0.f), v1 = v0, v2 = v0, v3 = v0;
    {
        float s, co; __sincosf(theta_in[c], &s, &co);
        if (l == (c >> 1)) {
            float2 e0 = make_float2(A * co, A * s), e1 = make_float2(-B * s, B * co);
            if (c & 1) { v2 = e0; v3 = e1; } else { v0 = e0; v1 = e1; }
        }
    }
    const float2* tev = (const float2*)theta_even + l;
    for (int j = 0; j < 254; ++j) {
        CoefF cf = make_coef_f(tev[j * 64]);
        float2 n0, n1, n2, n3;
        n0.x = cf.a0.x*v0.x - cf.a0.y*v0.y - B*v1.y;  n0.y = cf.a0.x*v0.y + cf.a0.y*v0.x + B*v1.x;
        n1.x = cf.b0.x*v0.x - cf.b0.y*v0.y + A*v1.x;  n1.y = cf.b0.x*v0.y + cf.b0.y*v0.x + A*v1.y;
        n2.x = cf.a1.x*v2.x - cf.a1.y*v2.y - B*v3.y;  n2.y = cf.a1.x*v2.y + cf.a1.y*v2.x + B*v3.x;
        n3.x = cf.b1.x*v2.x - cf.b1.y*v2.y + A*v3.x;  n3.y = cf.b1.x*v2.y + cf.b1.y*v2.x + A*v3.y;
        v0 = n0; v1 = n1; v2 = n2; v3 = n3;
        if ((j & 1) == 0) {
            float nx = wshl1(v0.x), ny = wshl1(v0.y);
            float px = wshr1(v3.x), py = wshr1(v3.y);
            float2 m0, m1, m2, m3;
            m0.x = ec0*v0.x - es0*py;  m0.y = ec0*v0.y + es0*px;
            m3.x = ec3*v3.x - es3*ny;  m3.y = ec3*v3.y + es3*nx;
            m1.x = C2*v1.x - S2*v2.y;  m1.y = C2*v1.y + S2*v2.x;
            m2.x = C2*v2.x - S2*v1.y;  m2.y = C2*v2.y + S2*v1.x;
            v0 = m0; v1 = m1; v2 = m2; v3 = m3;
        }
    }
    CoefF cf = make_coef_f(tev[254 * 64]);
    float2 o0, o1;
    o0.x = cf.a0.x*v0.x - cf.a0.y*v0.y - B*v1.y;  o0.y = cf.a0.x*v0.y + cf.a0.y*v0.x + B*v1.x;
    o1.x = cf.a1.x*v2.x - cf.a1.y*v2.y - B*v3.y;  o1.y = cf.a1.x*v2.y + cf.a1.y*v2.x + B*v3.x;
    float2 tho = ((const float2*)theta_out)[l];
    float s0, c0, s1, c1;
    __sincosf(tho.x, &s0, &c0);
    __sincosf(tho.y, &s1, &c1);
    out[(2 * l)     * NN + c] = c0 * o0.x - s0 * o0.y;
    out[(2 * l + 1) * NN + c] = c1 * o1.x - s1 * o1.y;
}

extern "C" void kernel_launch(void* const* d_in, const int* in_sizes, int n_in,
                              void* d_out, int out_size, void* d_ws, size_t ws_size,
                              hipStream_t stream) {
    // Identify inputs by SIZE: theta_even is the unique large (32640) array;
    // the two 128-elem arrays keep relative order (theta_in before theta_out).
    int ev = 0;
    for (int i = 0; i < n_in; ++i) if (in_sizes[i] > 1000) ev = i;
    int a = -1, b = -1;
    for (int i = 0; i < n_in; ++i) {
        if (i == ev) continue;
        if (a < 0) a = i; else if (b < 0) b = i;
    }
    const float* th_in  = (const float*)d_in[a];
    const float* th_ev  = (const float*)d_in[ev];
    const float* th_out = (const float*)d_in[b];

    const size_t tab_bytes = (size_t)255 * 128 * sizeof(float2);   // 261120
    if (ws_size >= tab_bytes) {
        float2* tab = (float2*)d_ws;
        coef_kernel<<<dim3(128), dim3(256), 0, stream>>>(th_ev, tab);
        mesh_lds_kernel<<<dim3(NN), dim3(64), 0, stream>>>(
            (const float4*)tab, th_in, th_out, (float*)d_out);
    } else {
        mesh_fallback<<<dim3(NN), dim3(64), 0, stream>>>(th_in, th_ev, th_out, (float*)d_out);
    }
}

// Round 15
// 29.870 us; speedup vs baseline: 1.2909x; 1.2909x over previous
//
#include <hip/hip_runtime.h>

#define NN 128   // modes

// ---- whole-wave lane shifts via DPP (wave_shl:1 / wave_shr:1), proven R9-R14 ----
__device__ __forceinline__ float wshl1(float x) {   // lane i <- lane i+1
    return __int_as_float(__builtin_amdgcn_update_dpp(
        __float_as_int(x), __float_as_int(x), 0x130, 0xf, 0xf, false));
}
__device__ __forceinline__ float wshr1(float x) {   // lane i <- lane i-1
    return __int_as_float(__builtin_amdgcn_update_dpp(
        __float_as_int(x), __float_as_int(x), 0x138, 0xf, 0xf, false));
}

// (cos,sin) pair for the lane's two even rows of one layer
__device__ __forceinline__ float4 make_cs(float2 th) {
    float s0, c0, s1, c1;
    __sincosf(th.x, &s0, &c0);
    __sincosf(th.y, &s1, &c1);
    return make_float4(c0, s0, c1, s1);
}

// ---------------- single fused kernel ----------------
// One wave per column c (128 blocks). Lane l holds rows 4l..4l+3 (4 complex).
// Static 8-deep theta ring (loads write consume slots directly, no rotation);
// coefficients (sincos) computed ONE layer ahead, off the state chain.
// Cross-lane via whole-wave DPP. Zero LDS, zero extra kernels.
__global__ __launch_bounds__(64) void mesh_fused_kernel(
    const float* __restrict__ theta_in,    // (128,)
    const float* __restrict__ theta_even,  // (255,128)
    const float* __restrict__ theta_out,   // (128,)
    float* __restrict__ out)               // (128,128) f32 = Re(arch)
{
    const int c = blockIdx.x;
    const int l = threadIdx.x;

    const float A  = sqrtf(0.95f * 0.505f);
    const float B  = sqrtf(0.95f * 0.495f);
    const float C2 = sqrtf(0.98f * 0.01f);
    const float S2 = sqrtf(0.98f * 0.99f);

    // branchless corner coeffs: row 0 (l==0, slot v0), row 255 (l==63, slot v3)
    const float ec0 = (l == 0)  ? S2 : C2, es0 = (l == 0)  ? 0.f : S2;
    const float ec3 = (l == 63) ? S2 : C2, es3 = (l == 63) ? 0.f : S2;

    // theta ring: lane l needs theta_even[j*128 + 2l .. 2l+1] = float2 at j*64+l
    const float2* TL = (const float2*)theta_even + l;
    float2 t0 = TL[0*64], t1 = TL[1*64], t2 = TL[2*64], t3 = TL[3*64],
           t4 = TL[4*64], t5 = TL[5*64], t6 = TL[6*64], t7 = TL[7*64];

    // init: column c after MMI_IN -> rows 2c: A e^{i th}, 2c+1: iB e^{i th}
    float2 v0 = make_float2(0.f, 0.f), v1 = v0, v2 = v0, v3 = v0;
    {
        float s, co;
        __sincosf(theta_in[c], &s, &co);
        float2 e0 = make_float2(A * co, A * s);
        float2 e1 = make_float2(-B * s, B * co);
        if (l == (c >> 1)) {
            if (c & 1) { v2 = e0; v3 = e1; }
            else       { v0 = e0; v1 = e1; }
        }
    }

    // rotate-then-mix layer (proven R11 math): t = (c0,s0,c1,s1)
    auto layer = [&](float4 t) {
        float rx = t.x * v0.x - t.y * v0.y;     // e^{i th} * v0
        float ry = t.x * v0.y + t.y * v0.x;
        float qx = t.z * v2.x - t.w * v2.y;     // e^{i th'} * v2
        float qy = t.z * v2.y + t.w * v2.x;
        float2 n0, n1, n2, n3;
        n0.x = A * rx   - B * v1.y;  n0.y = A * ry   + B * v1.x;
        n1.x = A * v1.x - B * ry;    n1.y = A * v1.y + B * rx;
        n2.x = A * qx   - B * v3.y;  n2.y = A * qy   + B * v3.x;
        n3.x = A * v3.x - B * qy;    n3.y = A * v3.y + B * qx;
        v0 = n0; v1 = n1; v2 = n2; v3 = n3;
    };
    auto crossl = [&]() {
        float nx = wshl1(v0.x), ny = wshl1(v0.y);   // lane l+1's v0
        float px = wshr1(v3.x), py = wshr1(v3.y);   // lane l-1's v3
        float2 m0, m1, m2, m3;
        m0.x = ec0 * v0.x - es0 * py;  m0.y = ec0 * v0.y + es0 * px;
        m3.x = ec3 * v3.x - es3 * ny;  m3.y = ec3 * v3.y + es3 * nx;
        m1.x = C2 * v1.x - S2 * v2.y;  m1.y = C2 * v1.y + S2 * v2.x;
        m2.x = C2 * v2.x - S2 * v1.y;  m2.y = C2 * v2.y + S2 * v1.x;
        v0 = m0; v1 = m1; v2 = m2; v3 = m3;
    };

    float4 cf = make_cs(t0);   // layer 0 coefficients

    // 31 batches of 8: layers 0..247. Slot k reloaded with theta[j8+8+k]
    // (only slot 7 can exceed 254: clamp, scalar). cfn uses the NEXT slot's
    // current value; load->use distance = 7 steps.
    for (int j8 = 0; j8 < 248; j8 += 8) {
        { t0 = TL[(j8+ 8)*64]; float4 cfn = make_cs(t1); layer(cf); crossl(); cf = cfn; }
        { t1 = TL[(j8+ 9)*64]; float4 cfn = make_cs(t2); layer(cf);           cf = cfn; }
        { t2 = TL[(j8+10)*64]; float4 cfn = make_cs(t3); layer(cf); crossl(); cf = cfn; }
        { t3 = TL[(j8+11)*64]; float4 cfn = make_cs(t4); layer(cf);           cf = cfn; }
        { t4 = TL[(j8+12)*64]; float4 cfn = make_cs(t5); layer(cf); crossl(); cf = cfn; }
        { t5 = TL[(j8+13)*64]; float4 cfn = make_cs(t6); layer(cf);           cf = cfn; }
        { t6 = TL[(j8+14)*64]; float4 cfn = make_cs(t7); layer(cf); crossl(); cf = cfn; }
        { int i7 = j8 + 15; if (i7 > 254) i7 = 254;
          t7 = TL[i7*64];      float4 cfn = make_cs(t0); layer(cf);           cf = cfn; }
    }
    // tail: layers 248..253 (t0..t5 hold theta[248..253]); cf = cs(theta[248])
    { float4 cfn = make_cs(t1); layer(cf); crossl(); cf = cfn; }   // 248
    { float4 cfn = make_cs(t2); layer(cf);           cf = cfn; }   // 249
    { float4 cfn = make_cs(t3); layer(cf); crossl(); cf = cfn; }   // 250
    { float4 cfn = make_cs(t4); layer(cf);           cf = cfn; }   // 251
    { float4 cfn = make_cs(t5); layer(cf); crossl(); cf = cfn; }   // 252
    { float4 cfn = make_cs(t6); layer(cf);           cf = cfn; }   // 253

    // cf = cs(theta[254]): final diag + MMI_OUT fold -> rows 2l, 2l+1
    float rx = cf.x * v0.x - cf.y * v0.y;
    float ry = cf.x * v0.y + cf.y * v0.x;
    float qx = cf.z * v2.x - cf.w * v2.y;
    float qy = cf.z * v2.y + cf.w * v2.x;
    float2 o0, o1;
    o0.x = A * rx - B * v1.y;  o0.y = A * ry + B * v1.x;
    o1.x = A * qx - B * v3.y;  o1.y = A * qy + B * v3.x;

    // diag(d_out) rotation, keep real part
    float2 tho = ((const float2*)theta_out)[l];
    float s0, c0, s1, c1;
    __sincosf(tho.x, &s0, &c0);
    __sincosf(tho.y, &s1, &c1);
    out[(2 * l)     * NN + c] = c0 * o0.x - s0 * o0.y;
    out[(2 * l + 1) * NN + c] = c1 * o1.x - s1 * o1.y;
}

extern "C" void kernel_launch(void* const* d_in, const int* in_sizes, int n_in,
                              void* d_out, int out_size, void* d_ws, size_t ws_size,
                              hipStream_t stream) {
    // Identify inputs by SIZE: theta_even is the unique large (32640) array;
    // the two 128-elem arrays keep relative order (theta_in before theta_out).
    int ev = 0;
    for (int i = 0; i < n_in; ++i) if (in_sizes[i] > 1000) ev = i;
    int a = -1, b = -1;
    for (int i = 0; i < n_in; ++i) {
        if (i == ev) continue;
        if (a < 0) a = i; else if (b < 0) b = i;
    }
    const float* th_in  = (const float*)d_in[a];
    const float* th_ev  = (const float*)d_in[ev];
    const float* th_out = (const float*)d_in[b];
    mesh_fused_kernel<<<dim3(NN), dim3(64), 0, stream>>>(
        th_in, th_ev, th_out, (float*)d_out);
}